// Round 14
// baseline (182.715 us; speedup 1.0000x reference)
//
#include <hip/hip_runtime.h>

#define DIM   1024
#define HEADS 16
#define NSEQ  2048
#define BATCH 2

typedef unsigned short u16;
typedef unsigned long long u64;
typedef __attribute__((ext_vector_type(8))) short bf16x8;    // 8 bf16 = 4 VGPRs
typedef __attribute__((ext_vector_type(4))) float f32x4;
typedef __attribute__((ext_vector_type(16))) float f32x16;

__device__ __forceinline__ u16 f2b(float f) {
  union { float f; unsigned u; } v; v.f = f;
  unsigned r = (v.u + 0x7fffu + ((v.u >> 16) & 1u)) >> 16;  // RNE
  return (u16)r;
}

// async global->LDS, 16B per lane; LDS dest is wave-uniform base + lane*16
__device__ __forceinline__ void g2l16(const u16* g, u16* l) {
  __builtin_amdgcn_global_load_lds(
      (const __attribute__((address_space(1))) void*)g,
      (__attribute__((address_space(3))) void*)l, 16, 0, 0);
}

// raw barrier with compiler-level memory fences on both sides: hardware-syncs
// waves WITHOUT draining vmcnt (unlike __syncthreads), while preventing the
// compiler from moving LDS reads / g2l16 issues across it.
__device__ __forceinline__ void fence_barrier() {
  asm volatile("" ::: "memory");
  __builtin_amdgcn_s_barrier();
  asm volatile("" ::: "memory");
}

// ---------------------------------------------------------------- fp32 -> bf16
// One fused kernel for all three tensors (saves 2 launches ~10 us, measured r2->r6).
// w_qkv's Q rows (first 1024*1024 elems) get scale*log2e folded in so the
// exp2 arg comes out of QK^T free.
#define N4_X  (4096 * 1024 / 4)
#define N4_W  (3072 * 1024 / 4)
#define N4_O  (1024 * 1024 / 4)
__global__ void cvt_all(const float* __restrict__ x, const float* __restrict__ wqkv,
                        const float* __restrict__ wout,
                        u16* __restrict__ xb, u16* __restrict__ wqkvb,
                        u16* __restrict__ woutb, float s) {
  int i = blockIdx.x * blockDim.x + threadIdx.x;   // grid sized exactly, no bound check
  const float* src; u16* dst; int j; float m = 1.0f;
  if (i < N4_X)            { src = x;    dst = xb;    j = i; }
  else if (i < N4_X + N4_W){ src = wqkv; dst = wqkvb; j = i - N4_X; if (j < 1024 * 1024 / 4) m = s; }
  else                     { src = wout; dst = woutb; j = i - N4_X - N4_W; }
  float4 f = ((const float4*)src)[j];
  union { u16 s[4]; u64 ll; } o;
  o.s[0] = f2b(f.x * m); o.s[1] = f2b(f.y * m);
  o.s[2] = f2b(f.z * m); o.s[3] = f2b(f.w * m);
  ((u64*)dst)[j] = o.ll;
}

// ------------------------------------------------- gemm1: C = A[M,K] @ Bt[N,K]^T
// r14: TRUE ASYNC PREFETCH + 256x192 tile. Ledger correction: r11/r12's "dbuf
// null" was confounded (tile reverted simultaneously) and r12 issued loads
// right before the wait (zero issue-to-wait distance). This version: per
// K-step [vmcnt(0): waits tile-t loads issued a FULL step ago (latency already
// elapsed) -> fence_barrier -> issue stage(t+1) -> compute t -> fence_barrier].
// stage(t+1) flies across the end barrier and the whole next-step wait gap.
// Hazards: WAR on buf^1 closed by two barriers between last read and next
// write; RAW closed by each wave's own vmcnt(0) before barrier A.
// Geometry: BM=256 BN=192 BK=64, 512 thr / 8 waves (wave 64x96, acc[4][6]);
// dbuf LDS (64+48)KiB*... = 112 KiB -> 1 block/CU; grid (16,16)=256 blocks
// = EXACTLY 1/CU, 100% fill, single round. FLOP/staged-byte 1.71 (vs 1.33).
// Staging/fragment address math = r2-proven chunk-XOR pattern (conflict-free),
// only row-group constants changed. Per-output k-order unchanged -> bit-identical.
__global__ __launch_bounds__(512, 1)
void gemm_bt(const u16* __restrict__ A, const u16* __restrict__ Bt,
             void* __restrict__ C, const float* __restrict__ bias,
             int M, int Nc, int K, int bf16_out) {
  __shared__ u16 As[2][256 * 64];   // 32 KiB each
  __shared__ u16 Bs[2][192 * 64];   // 24 KiB each
  const int tid  = threadIdx.x;
  const int wave = tid >> 6, lane = tid & 63;
  const int l15  = lane & 15, quad = lane >> 4;
  const int m0 = blockIdx.y * 256, n0 = blockIdx.x * 192;
  const int wm = (wave >> 1) * 64, wn = (wave & 1) * 96;
  const int rowoff = lane >> 3, ckx = lane & 7;

  f32x4 acc[4][6] = {};
  const int nk = K >> 6;

  // prologue: stage tile 0 into buf 0 (7 loads/thread)
#pragma unroll
  for (int c = 0; c < 4; ++c) {               // A: 256 rows, 4 issues/thread
    int bse = wave * 32 + c * 8;
    int r  = bse + rowoff;
    int ck = ckx ^ (r & 7);
    g2l16(A + (size_t)(m0 + r) * K + ck * 8, &As[0][bse * 64]);
  }
#pragma unroll
  for (int c = 0; c < 3; ++c) {               // B: 192 rows, 3 issues/thread
    int bse = wave * 24 + c * 8;
    int r  = bse + rowoff;
    int ck = ckx ^ (r & 7);
    g2l16(Bt + (size_t)(n0 + r) * K + ck * 8, &Bs[0][bse * 64]);
  }

  for (int t = 0; t < nk; ++t) {
    const int buf = t & 1;
    // tile t's loads were issued one full K-step ago -> residual wait ~0
    asm volatile("s_waitcnt vmcnt(0)" ::: "memory");
    fence_barrier();                          // buf complete block-wide
    if (t + 1 < nk) {                         // issue EARLY: flies across the
      const int kt = (t + 1) << 6;            // rest of this step + end barrier
#pragma unroll
      for (int c = 0; c < 4; ++c) {
        int bse = wave * 32 + c * 8;
        int r  = bse + rowoff;
        int ck = ckx ^ (r & 7);
        g2l16(A + (size_t)(m0 + r) * K + kt + ck * 8, &As[buf ^ 1][bse * 64]);
      }
#pragma unroll
      for (int c = 0; c < 3; ++c) {
        int bse = wave * 24 + c * 8;
        int r  = bse + rowoff;
        int ck = ckx ^ (r & 7);
        g2l16(Bt + (size_t)(n0 + r) * K + kt + ck * 8, &Bs[buf ^ 1][bse * 64]);
      }
    }
#pragma unroll
    for (int ks = 0; ks < 2; ++ks) {
      bf16x8 a[4], b[6];
      int ch = ks * 4 + quad;
#pragma unroll
      for (int i = 0; i < 4; ++i) {
        int ra = wm + i * 16 + l15;
        a[i] = *(const bf16x8*)&As[buf][ra * 64 + ((ch ^ (ra & 7)) << 3)];
      }
#pragma unroll
      for (int j = 0; j < 6; ++j) {
        int rb = wn + j * 16 + l15;
        b[j] = *(const bf16x8*)&Bs[buf][rb * 64 + ((ch ^ (rb & 7)) << 3)];
      }
#pragma unroll
      for (int i = 0; i < 4; ++i)
#pragma unroll
        for (int j = 0; j < 6; ++j)
          acc[i][j] = __builtin_amdgcn_mfma_f32_16x16x32_bf16(a[i], b[j], acc[i][j], 0, 0, 0);
    }
    fence_barrier();                          // all waves done reading buf
  }

#pragma unroll
  for (int i = 0; i < 4; ++i)
#pragma unroll
    for (int j = 0; j < 6; ++j) {
      int row = m0 + wm + i * 16 + quad * 4;
      int col = n0 + wn + j * 16 + l15;
#pragma unroll
      for (int r = 0; r < 4; ++r) {
        float v = acc[i][j][r];
        if (bf16_out) ((u16*)C)[(size_t)(row + r) * Nc + col] = f2b(v);
        else          ((float*)C)[(size_t)(row + r) * Nc + col] = v + bias[col];
      }
    }
}

// ------------------------------------------- gemm2: C = A[M,K] @ Bt^T + bias (f32)
// r14: same async structure at 128x128/BK=64 (r2-proven acc[4][4] fragment code
// verbatim). dbuf LDS 64 KiB; grid (8,32)=256 blocks = 1/CU full fill.
__global__ __launch_bounds__(256, 2)
void gemm_bt_f32(const u16* __restrict__ A, const u16* __restrict__ Bt,
                 float* __restrict__ C, const float* __restrict__ bias,
                 int M, int Nc, int K) {
  __shared__ u16 As[2][128 * 64];
  __shared__ u16 Bs[2][128 * 64];
  const int tid  = threadIdx.x;
  const int wave = tid >> 6, lane = tid & 63;
  const int l15  = lane & 15, quad = lane >> 4;
  const int m0 = blockIdx.y * 128, n0 = blockIdx.x * 128;
  const int wm = (wave >> 1) * 64, wn = (wave & 1) * 64;
  const int rb = wave * 32;
  const int rowoff = lane >> 3, ckx = lane & 7;

  f32x4 acc[4][4] = {};
  const int nk = K >> 6;

  // prologue: stage tile 0 into buf 0 (8 loads/thread)
#pragma unroll
  for (int c = 0; c < 4; ++c) {
    int bse = rb + c * 8;
    int r  = bse + rowoff;
    int ck = ckx ^ (r & 7);
    g2l16(A  + (size_t)(m0 + r) * K + ck * 8, &As[0][bse * 64]);
    g2l16(Bt + (size_t)(n0 + r) * K + ck * 8, &Bs[0][bse * 64]);
  }

  for (int t = 0; t < nk; ++t) {
    const int buf = t & 1;
    asm volatile("s_waitcnt vmcnt(0)" ::: "memory");
    fence_barrier();
    if (t + 1 < nk) {
      const int kt = (t + 1) << 6;
#pragma unroll
      for (int c = 0; c < 4; ++c) {
        int bse = rb + c * 8;
        int r  = bse + rowoff;
        int ck = ckx ^ (r & 7);
        g2l16(A  + (size_t)(m0 + r) * K + kt + ck * 8, &As[buf ^ 1][bse * 64]);
        g2l16(Bt + (size_t)(n0 + r) * K + kt + ck * 8, &Bs[buf ^ 1][bse * 64]);
      }
    }
#pragma unroll
    for (int ks = 0; ks < 2; ++ks) {
      bf16x8 a[4], b[4];
      int ch = ks * 4 + quad;
#pragma unroll
      for (int i = 0; i < 4; ++i) {
        int ra  = wm + i * 16 + l15;
        a[i] = *(const bf16x8*)&As[buf][ra * 64 + ((ch ^ (ra & 7)) << 3)];
        int rb2 = wn + i * 16 + l15;
        b[i] = *(const bf16x8*)&Bs[buf][rb2 * 64 + ((ch ^ (rb2 & 7)) << 3)];
      }
#pragma unroll
      for (int i = 0; i < 4; ++i)
#pragma unroll
        for (int j = 0; j < 4; ++j)
          acc[i][j] = __builtin_amdgcn_mfma_f32_16x16x32_bf16(a[i], b[j], acc[i][j], 0, 0, 0);
    }
    fence_barrier();
  }

#pragma unroll
  for (int i = 0; i < 4; ++i)
#pragma unroll
    for (int j = 0; j < 4; ++j) {
      int row = m0 + wm + i * 16 + quad * 4;
      int col = n0 + wn + j * 16 + l15;
#pragma unroll
      for (int r = 0; r < 4; ++r)
        C[(size_t)(row + r) * Nc + col] = acc[i][j][r] + bias[col];
    }
}

// --------------------------------------------------- flash attention v8 (FROZEN)
// 53.2-54 us stable (r9/r10/r12/r13): v4b structure + setprio (T5) + v_perm
// 3-op pack (bit-identical, VGPR 104, no spill). Latency-plateaued (r9: VALU
// cuts don't move the clock; LDS/VALU/MFMA all ~moderately busy, dependency-
// chain bound at 2 waves/SIMD). History: r1 cvt_pk pack = rounding fail;
// r5 in-place exp2 = spill; r3/r4 KVBLK=64 split = -20% efficiency.
// grid: (B*H, N/128), 256 threads, 2 blocks/CU.
__global__ __launch_bounds__(256, 2)
void attn(const u16* __restrict__ qkv, u16* __restrict__ outp) {
  __shared__ u16 Ks[2][128 * 64];    // K tile / Q staging, chunk-swizzle c^(row&7)
  __shared__ u16 Vts[2][64 * 128];   // permuted V^T, chunk-swizzle c^((d+(d>>3))&15)
  const int tid  = threadIdx.x;
  const int wave = tid >> 6, lane = tid & 63;
  const int l31  = lane & 31, h = lane >> 5;
  const int b = blockIdx.x >> 4, hd = blockIdx.x & 15;
  const int q0 = blockIdx.y * 128;
  const u16* base = qkv + (size_t)b * NSEQ * 3072;
  const int qoff = hd * 64, koff = DIM + hd * 64, voff = 2 * DIM + hd * 64;
  const int dc = tid & 7, j0l = (tid >> 3) * 4;   // V staging: this thread's d-chunk, j-group
  // V store position for j0l (pos(j) = ((j>>4)*2+((j>>2)&1))*8 + 4*((j>>3)&1) + (j&3))
  const int vchunk = (j0l >> 4) * 2 + ((j0l >> 2) & 1);
  const int vboff  = 4 * ((j0l >> 3) & 1);

  union V4 { uint4 q; u16 s[8]; };
  union PA { unsigned w[4]; bf16x8 f; };

  // ---- stage Q (128 rows) into Ks[0], pull B-fragments
#pragma unroll
  for (int c = 0; c < 4; ++c) {
    int bse = wave * 32 + c * 8;
    g2l16(base + (size_t)(q0 + bse + (lane >> 3)) * 3072 + qoff + (((lane & 7) ^ ((lane >> 3) & 7)) << 3),
          &Ks[0][bse * 64]);
  }
  __syncthreads();
  bf16x8 qf[4];
  {
    int qr = wave * 32 + l31;
#pragma unroll
    for (int kd = 0; kd < 4; ++kd)
      qf[kd] = *(const bf16x8*)&Ks[0][qr * 64 + (((kd * 2 + h) ^ (qr & 7)) << 3)];
  }
  __syncthreads();

  // ---- stage tile 0
  V4 vr[4];
#pragma unroll
  for (int c = 0; c < 4; ++c) {
    int bse = wave * 32 + c * 8;
    g2l16(base + (size_t)(bse + (lane >> 3)) * 3072 + koff + (((lane & 7) ^ ((lane >> 3) & 7)) << 3),
          &Ks[0][bse * 64]);
  }
#pragma unroll
  for (int e = 0; e < 4; ++e)
    vr[e].q = *(const uint4*)(base + (size_t)(j0l + e) * 3072 + voff + dc * 8);
#pragma unroll
  for (int u = 0; u < 8; ++u) {
    int d = dc * 8 + u;
    unsigned w0 = (unsigned)vr[0].s[u] | ((unsigned)vr[1].s[u] << 16);
    unsigned w1 = (unsigned)vr[2].s[u] | ((unsigned)vr[3].s[u] << 16);
    *(u64*)&Vts[0][d * 128 + ((vchunk ^ ((d + (d >> 3)) & 15)) << 3) + vboff] =
        (u64)w0 | ((u64)w1 << 32);
  }
  __syncthreads();

  float lrun = 0.0f;
  f32x16 oacc[2] = {};

  for (int t = 0; t < 16; ++t) {
    const int pbuf = t & 1;
    if (t < 15) {
      const int j0n = (t + 1) * 128;
#pragma unroll
      for (int c = 0; c < 4; ++c) {
        int bse = wave * 32 + c * 8;
        g2l16(base + (size_t)(j0n + bse + (lane >> 3)) * 3072 + koff + (((lane & 7) ^ ((lane >> 3) & 7)) << 3),
              &Ks[pbuf ^ 1][bse * 64]);
      }
#pragma unroll
      for (int e = 0; e < 4; ++e)
        vr[e].q = *(const uint4*)(base + (size_t)(j0n + j0l + e) * 3072 + voff + dc * 8);
    }

    // ---- S^T = K Q^T (exp2-ready logits: scale*log2e folded into Q)
    f32x16 sc[4] = {};
    __builtin_amdgcn_s_setprio(1);
#pragma unroll
    for (int kd = 0; kd < 4; ++kd) {
      bf16x8 kb[4];
#pragma unroll
      for (int ni = 0; ni < 4; ++ni) {
        int kr = ni * 32 + l31;
        kb[ni] = *(const bf16x8*)&Ks[pbuf][kr * 64 + (((kd * 2 + h) ^ (kr & 7)) << 3)];
      }
#pragma unroll
      for (int ni = 0; ni < 4; ++ni)
        sc[ni] = __builtin_amdgcn_mfma_f32_32x32x16_bf16(kb[ni], qf[kd], sc[ni], 0, 0, 0);
    }
    __builtin_amdgcn_s_setprio(0);

    // ---- exp2, l-accumulate, pack P directly into A-fragments (no shfl)
    PA pa[8];
#pragma unroll
    for (int ni = 0; ni < 4; ++ni) {
      f32x16 p;
#pragma unroll
      for (int r = 0; r < 16; ++r) p[r] = __builtin_amdgcn_exp2f(sc[ni][r]);
      float s0 = (p[0] + p[1]) + (p[2] + p[3]);
      float s1 = (p[4] + p[5]) + (p[6] + p[7]);
      float s2 = (p[8] + p[9]) + (p[10] + p[11]);
      float s3 = (p[12] + p[13]) + (p[14] + p[15]);
      lrun += (s0 + s1) + (s2 + s3);
#pragma unroll
      for (int ks2 = 0; ks2 < 2; ++ks2)
#pragma unroll
        for (int i = 0; i < 4; ++i) {
          unsigned lo = __float_as_uint(p[8 * ks2 + 2 * i])     + 0x8000u;
          unsigned hi = __float_as_uint(p[8 * ks2 + 2 * i + 1]) + 0x8000u;
          pa[2 * ni + ks2].w[i] = __builtin_amdgcn_perm(hi, lo, 0x07060302u);
        }
    }

    // ---- O += P V  (V rows pre-permuted so pa's k-order matches)
    __builtin_amdgcn_s_setprio(1);
#pragma unroll
    for (int f = 0; f < 8; ++f) {
      bf16x8 vb[2];
#pragma unroll
      for (int nd = 0; nd < 2; ++nd) {
        int d = nd * 32 + l31;
        vb[nd] = *(const bf16x8*)&Vts[pbuf][d * 128 + (((2 * f + h) ^ ((d + (d >> 3)) & 15)) << 3)];
      }
#pragma unroll
      for (int nd = 0; nd < 2; ++nd)
        oacc[nd] = __builtin_amdgcn_mfma_f32_32x32x16_bf16(pa[f].f, vb[nd], oacc[nd], 0, 0, 0);
    }
    __builtin_amdgcn_s_setprio(0);

    // ---- commit prefetched V (permuted positions, dc-mixed swizzle: conflict-free)
    if (t < 15) {
#pragma unroll
      for (int u = 0; u < 8; ++u) {
        int d = dc * 8 + u;
        unsigned w0 = (unsigned)vr[0].s[u] | ((unsigned)vr[1].s[u] << 16);
        unsigned w1 = (unsigned)vr[2].s[u] | ((unsigned)vr[3].s[u] << 16);
        *(u64*)&Vts[pbuf ^ 1][d * 128 + ((vchunk ^ ((d + (d >> 3)) & 15)) << 3) + vboff] =
            (u64)w0 | ((u64)w1 << 32);
      }
    }
    __syncthreads();
  }

  // ---- epilogue: combine l halves (1 shfl), normalize, store
  float l = lrun + __shfl_xor(lrun, 32, 64);
  float linv = 1.0f / l;
#pragma unroll
  for (int r = 0; r < 16; ++r) {
    int rowloc = (r & 3) + 8 * (r >> 2) + 4 * h;
    float lb = __shfl(linv, rowloc, 64);
    int row = q0 + wave * 32 + rowloc;
#pragma unroll
    for (int nd = 0; nd < 2; ++nd)
      outp[((size_t)b * NSEQ + row) * DIM + hd * 64 + nd * 32 + l31] = f2b(oacc[nd][r] * lb);
  }
}

extern "C" void kernel_launch(void* const* d_in, const int* in_sizes, int n_in,
                              void* d_out, int out_size, void* d_ws, size_t ws_size,
                              hipStream_t stream) {
  const float* x     = (const float*)d_in[0];
  const float* w_qkv = (const float*)d_in[1];
  const float* w_out = (const float*)d_in[2];
  const float* b_out = (const float*)d_in[3];
  float* outp = (float*)d_out;

  u16* xb    = (u16*)d_ws;                        // 4096*1024
  u16* wqkvb = xb    + (size_t)4096 * 1024;       // 3072*1024
  u16* woutb = wqkvb + (size_t)3072 * 1024;       // 1024*1024
  u16* qkvb  = woutb + (size_t)1024 * 1024;       // 4096*3072
  u16* attnb = qkvb  + (size_t)4096 * 3072;       // 4096*1024

  const float C2 = 0.03125f * 1.44269504088896340736f;  // dim^-0.5 * log2(e)

  cvt_all<<<(N4_X + N4_W + N4_O) / 256, 256, 0, stream>>>(x, w_qkv, w_out,
                                                          xb, wqkvb, woutb, C2);

  gemm_bt<<<dim3(16, 16), 512, 0, stream>>>(xb, wqkvb, qkvb, nullptr, 4096, 3072, 1024, 1);
  attn<<<dim3(32, 16), 256, 0, stream>>>(qkvb, attnb);
  gemm_bt_f32<<<dim3(8, 32), 256, 0, stream>>>(attnb, woutb, outp, b_out, 4096, 1024, 1024);
}

// Round 15
// 172.741 us; speedup vs baseline: 1.0577x; 1.0577x over previous
//
#include <hip/hip_runtime.h>

#define DIM   1024
#define HEADS 16
#define NSEQ  2048
#define BATCH 2

typedef unsigned short u16;
typedef unsigned long long u64;
typedef __attribute__((ext_vector_type(8))) short bf16x8;    // 8 bf16 = 4 VGPRs
typedef __attribute__((ext_vector_type(4))) float f32x4;
typedef __attribute__((ext_vector_type(16))) float f32x16;

__device__ __forceinline__ u16 f2b(float f) {
  union { float f; unsigned u; } v; v.f = f;
  unsigned r = (v.u + 0x7fffu + ((v.u >> 16) & 1u)) >> 16;  // RNE
  return (u16)r;
}

// async global->LDS, 16B per lane; LDS dest is wave-uniform base + lane*16
__device__ __forceinline__ void g2l16(const u16* g, u16* l) {
  __builtin_amdgcn_global_load_lds(
      (const __attribute__((address_space(1))) void*)g,
      (__attribute__((address_space(3))) void*)l, 16, 0, 0);
}

// ---------------------------------------------------------------- fp32 -> bf16
// One fused kernel for all three tensors (saves 2 launches ~10 us, measured r2->r6).
// w_qkv's Q rows (first 1024*1024 elems) get scale*log2e folded in so the
// exp2 arg comes out of QK^T free.
#define N4_X  (4096 * 1024 / 4)
#define N4_W  (3072 * 1024 / 4)
#define N4_O  (1024 * 1024 / 4)
__global__ void cvt_all(const float* __restrict__ x, const float* __restrict__ wqkv,
                        const float* __restrict__ wout,
                        u16* __restrict__ xb, u16* __restrict__ wqkvb,
                        u16* __restrict__ woutb, float s) {
  int i = blockIdx.x * blockDim.x + threadIdx.x;   // grid sized exactly, no bound check
  const float* src; u16* dst; int j; float m = 1.0f;
  if (i < N4_X)            { src = x;    dst = xb;    j = i; }
  else if (i < N4_X + N4_W){ src = wqkv; dst = wqkvb; j = i - N4_X; if (j < 1024 * 1024 / 4) m = s; }
  else                     { src = wout; dst = woutb; j = i - N4_X - N4_W; }
  float4 f = ((const float4*)src)[j];
  union { u16 s[4]; u64 ll; } o;
  o.s[0] = f2b(f.x * m); o.s[1] = f2b(f.y * m);
  o.s[2] = f2b(f.z * m); o.s[3] = f2b(f.w * m);
  ((u64*)dst)[j] = o.ll;
}

// ------------------------------------------------- gemm1: C = A[M,K] @ Bt[N,K]^T
// r15: = r13 anchor (176.4 us) + T1 XCD-aware block swizzle (only change).
// Mechanism: x-major dispatch round-robins consecutive blocks (which share a
// 256 KB A-panel) across 8 non-coherent XCD L2s; bijective chunking gives each
// XCD a run of 48 consecutive tiles -> A-panel becomes L2-resident per XCD.
// nwg=384 %8==0 -> simple (id&7)*cpx+(id>>3) form is bijective; remap only
// permutes tile assignment -> bit-identical output.
// Structural ledger at this shape (K=1024), all CLOSED:
//   r5 blocks/CU null; r7 BK null; r10 wave-tile null;
//   r11/r12/r14 async dbuf (3 forms incl. issue-early) -> -6..-7 us each
//   (dbuf halves residency; loses m114's free inter-block overlap).
__global__ __launch_bounds__(256, 2)
void gemm_bt(const u16* __restrict__ A, const u16* __restrict__ Bt,
             void* __restrict__ C, const float* __restrict__ bias,
             int M, int Nc, int K, int bf16_out) {
  __shared__ u16 As[128 * 64];   // 16 KiB
  __shared__ u16 Bs[256 * 64];   // 32 KiB
  const int tid  = threadIdx.x;
  const int wave = tid >> 6, lane = tid & 63;
  const int l15  = lane & 15, quad = lane >> 4;
  // ---- XCD swizzle (T1): bijective chunked remap of linear block id
  const int id   = blockIdx.x + gridDim.x * blockIdx.y;
  const int cpx  = (gridDim.x * gridDim.y) >> 3;          // 384/8 = 48
  const int tile = (id & 7) * cpx + (id >> 3);
  const int bx   = tile % gridDim.x, by = tile / gridDim.x;
  const int m0 = by * 128, n0 = bx * 256;
  const int wm = (wave >> 1) * 64, wn = (wave & 1) * 128;

  f32x4 acc[4][8] = {};

  for (int kt = 0; kt < K; kt += 64) {
#pragma unroll
    for (int c = 0; c < 4; ++c) {            // A: 128 rows, 4 issues/wave
      int bse = wave * 32 + c * 8;
      int r  = bse + (lane >> 3);
      int ck = (lane & 7) ^ (r & 7);
      g2l16(A + (size_t)(m0 + r) * K + kt + ck * 8, &As[bse * 64]);
    }
#pragma unroll
    for (int c = 0; c < 8; ++c) {            // B: 256 rows, 8 issues/wave
      int bse = wave * 64 + c * 8;
      int r  = bse + (lane >> 3);
      int ck = (lane & 7) ^ (r & 7);
      g2l16(Bt + (size_t)(n0 + r) * K + kt + ck * 8, &Bs[bse * 64]);
    }
    __syncthreads();
#pragma unroll
    for (int ks = 0; ks < 2; ++ks) {
      bf16x8 a[4], b[8];
      int ch = ks * 4 + quad;
#pragma unroll
      for (int i = 0; i < 4; ++i) {
        int ra = wm + i * 16 + l15;
        a[i] = *(const bf16x8*)&As[ra * 64 + ((ch ^ (ra & 7)) << 3)];
      }
#pragma unroll
      for (int j = 0; j < 8; ++j) {
        int rb2 = wn + j * 16 + l15;
        b[j] = *(const bf16x8*)&Bs[rb2 * 64 + ((ch ^ (rb2 & 7)) << 3)];
      }
#pragma unroll
      for (int i = 0; i < 4; ++i)
#pragma unroll
        for (int j = 0; j < 8; ++j)
          acc[i][j] = __builtin_amdgcn_mfma_f32_16x16x32_bf16(a[i], b[j], acc[i][j], 0, 0, 0);
    }
    __syncthreads();
  }

#pragma unroll
  for (int i = 0; i < 4; ++i)
#pragma unroll
    for (int j = 0; j < 8; ++j) {
      int row = m0 + wm + i * 16 + quad * 4;
      int col = n0 + wn + j * 16 + l15;
#pragma unroll
      for (int r = 0; r < 4; ++r) {
        float v = acc[i][j][r];
        if (bf16_out) ((u16*)C)[(size_t)(row + r) * Nc + col] = f2b(v);
        else          ((float*)C)[(size_t)(row + r) * Nc + col] = v + bias[col];
      }
    }
}

// ------------------------------------------- gemm2: C = A[M,K] @ Bt[64-col tile]
// r15: = r13/r8 form (tile 128x64, BK=128, single-buffered, 512 blocks = 2/CU)
// + T1 XCD swizzle (nwg=512 %8==0, bijective).
__global__ __launch_bounds__(256, 2)
void gemm_bt_n64(const u16* __restrict__ A, const u16* __restrict__ Bt,
                 float* __restrict__ C, const float* __restrict__ bias,
                 int M, int Nc, int K) {
  __shared__ u16 As[128 * 128];   // 32 KiB
  __shared__ u16 Bs[64 * 128];    // 16 KiB
  const int tid  = threadIdx.x;
  const int wave = tid >> 6, lane = tid & 63;
  const int l15  = lane & 15, quad = lane >> 4;
  const int id   = blockIdx.x + gridDim.x * blockIdx.y;
  const int cpx  = (gridDim.x * gridDim.y) >> 3;          // 512/8 = 64
  const int tile = (id & 7) * cpx + (id >> 3);
  const int bx   = tile % gridDim.x, by = tile / gridDim.x;
  const int m0 = by * 128, n0 = bx * 64;
  const int wm = wave * 32;

  f32x4 acc[2][4] = {};

  for (int kt = 0; kt < K; kt += 128) {
#pragma unroll
    for (int c = 0; c < 8; ++c) {             // A: 128 rows, 8 issues/wave
      int r  = wave * 32 + c * 4 + (lane >> 4);
      int ck = (lane & 15) ^ (r & 15);
      g2l16(A + (size_t)(m0 + r) * K + kt + ck * 8, &As[(wave * 32 + c * 4) * 128]);
    }
#pragma unroll
    for (int c = 0; c < 4; ++c) {             // B: 64 rows, 4 issues/wave
      int r  = wave * 16 + c * 4 + (lane >> 4);
      int ck = (lane & 15) ^ (r & 15);
      g2l16(Bt + (size_t)(n0 + r) * K + kt + ck * 8, &Bs[(wave * 16 + c * 4) * 128]);
    }
    __syncthreads();
#pragma unroll
    for (int ks = 0; ks < 4; ++ks) {
      bf16x8 a[2], b[4];
      int ch = ks * 4 + quad;
#pragma unroll
      for (int i = 0; i < 2; ++i) {
        int ra = wm + i * 16 + l15;
        a[i] = *(const bf16x8*)&As[ra * 128 + ((ch ^ (ra & 15)) << 3)];
      }
#pragma unroll
      for (int j = 0; j < 4; ++j) {
        int rb2 = j * 16 + l15;               // all waves broadcast-read B rows
        b[j] = *(const bf16x8*)&Bs[rb2 * 128 + ((ch ^ (rb2 & 15)) << 3)];
      }
#pragma unroll
      for (int i = 0; i < 2; ++i)
#pragma unroll
        for (int j = 0; j < 4; ++j)
          acc[i][j] = __builtin_amdgcn_mfma_f32_16x16x32_bf16(a[i], b[j], acc[i][j], 0, 0, 0);
    }
    __syncthreads();
  }

#pragma unroll
  for (int i = 0; i < 2; ++i)
#pragma unroll
    for (int j = 0; j < 4; ++j) {
      int row = m0 + wm + i * 16 + quad * 4;
      int col = n0 + j * 16 + l15;
#pragma unroll
      for (int r = 0; r < 4; ++r)
        C[(size_t)(row + r) * Nc + col] = acc[i][j][r] + bias[col];
    }
}

// --------------------------------------------------- flash attention v8 (FROZEN)
// 53.2-55 us stable (r9-r14): v4b structure + setprio (T5) + v_perm 3-op pack
// (bit-identical, VGPR 104, no spill). Latency-plateaued (r9: VALU cuts don't
// move the clock; dependency-chain bound at 2 waves/SIMD). History: r1 cvt_pk
// pack = rounding fail; r5 in-place exp2 = spill; r3/r4 KVBLK=64 split = -20%.
// grid: (B*H, N/128), 256 threads, 2 blocks/CU.
__global__ __launch_bounds__(256, 2)
void attn(const u16* __restrict__ qkv, u16* __restrict__ outp) {
  __shared__ u16 Ks[2][128 * 64];    // K tile / Q staging, chunk-swizzle c^(row&7)
  __shared__ u16 Vts[2][64 * 128];   // permuted V^T, chunk-swizzle c^((d+(d>>3))&15)
  const int tid  = threadIdx.x;
  const int wave = tid >> 6, lane = tid & 63;
  const int l31  = lane & 31, h = lane >> 5;
  const int b = blockIdx.x >> 4, hd = blockIdx.x & 15;
  const int q0 = blockIdx.y * 128;
  const u16* base = qkv + (size_t)b * NSEQ * 3072;
  const int qoff = hd * 64, koff = DIM + hd * 64, voff = 2 * DIM + hd * 64;
  const int dc = tid & 7, j0l = (tid >> 3) * 4;   // V staging: this thread's d-chunk, j-group
  // V store position for j0l (pos(j) = ((j>>4)*2+((j>>2)&1))*8 + 4*((j>>3)&1) + (j&3))
  const int vchunk = (j0l >> 4) * 2 + ((j0l >> 2) & 1);
  const int vboff  = 4 * ((j0l >> 3) & 1);

  union V4 { uint4 q; u16 s[8]; };
  union PA { unsigned w[4]; bf16x8 f; };

  // ---- stage Q (128 rows) into Ks[0], pull B-fragments
#pragma unroll
  for (int c = 0; c < 4; ++c) {
    int bse = wave * 32 + c * 8;
    g2l16(base + (size_t)(q0 + bse + (lane >> 3)) * 3072 + qoff + (((lane & 7) ^ ((lane >> 3) & 7)) << 3),
          &Ks[0][bse * 64]);
  }
  __syncthreads();
  bf16x8 qf[4];
  {
    int qr = wave * 32 + l31;
#pragma unroll
    for (int kd = 0; kd < 4; ++kd)
      qf[kd] = *(const bf16x8*)&Ks[0][qr * 64 + (((kd * 2 + h) ^ (qr & 7)) << 3)];
  }
  __syncthreads();

  // ---- stage tile 0
  V4 vr[4];
#pragma unroll
  for (int c = 0; c < 4; ++c) {
    int bse = wave * 32 + c * 8;
    g2l16(base + (size_t)(bse + (lane >> 3)) * 3072 + koff + (((lane & 7) ^ ((lane >> 3) & 7)) << 3),
          &Ks[0][bse * 64]);
  }
#pragma unroll
  for (int e = 0; e < 4; ++e)
    vr[e].q = *(const uint4*)(base + (size_t)(j0l + e) * 3072 + voff + dc * 8);
#pragma unroll
  for (int u = 0; u < 8; ++u) {
    int d = dc * 8 + u;
    unsigned w0 = (unsigned)vr[0].s[u] | ((unsigned)vr[1].s[u] << 16);
    unsigned w1 = (unsigned)vr[2].s[u] | ((unsigned)vr[3].s[u] << 16);
    *(u64*)&Vts[0][d * 128 + ((vchunk ^ ((d + (d >> 3)) & 15)) << 3) + vboff] =
        (u64)w0 | ((u64)w1 << 32);
  }
  __syncthreads();

  float lrun = 0.0f;
  f32x16 oacc[2] = {};

  for (int t = 0; t < 16; ++t) {
    const int pbuf = t & 1;
    if (t < 15) {
      const int j0n = (t + 1) * 128;
#pragma unroll
      for (int c = 0; c < 4; ++c) {
        int bse = wave * 32 + c * 8;
        g2l16(base + (size_t)(j0n + bse + (lane >> 3)) * 3072 + koff + (((lane & 7) ^ ((lane >> 3) & 7)) << 3),
              &Ks[pbuf ^ 1][bse * 64]);
      }
#pragma unroll
      for (int e = 0; e < 4; ++e)
        vr[e].q = *(const uint4*)(base + (size_t)(j0n + j0l + e) * 3072 + voff + dc * 8);
    }

    // ---- S^T = K Q^T (exp2-ready logits: scale*log2e folded into Q)
    f32x16 sc[4] = {};
    __builtin_amdgcn_s_setprio(1);
#pragma unroll
    for (int kd = 0; kd < 4; ++kd) {
      bf16x8 kb[4];
#pragma unroll
      for (int ni = 0; ni < 4; ++ni) {
        int kr = ni * 32 + l31;
        kb[ni] = *(const bf16x8*)&Ks[pbuf][kr * 64 + (((kd * 2 + h) ^ (kr & 7)) << 3)];
      }
#pragma unroll
      for (int ni = 0; ni < 4; ++ni)
        sc[ni] = __builtin_amdgcn_mfma_f32_32x32x16_bf16(kb[ni], qf[kd], sc[ni], 0, 0, 0);
    }
    __builtin_amdgcn_s_setprio(0);

    // ---- exp2, l-accumulate, pack P directly into A-fragments (no shfl)
    PA pa[8];
#pragma unroll
    for (int ni = 0; ni < 4; ++ni) {
      f32x16 p;
#pragma unroll
      for (int r = 0; r < 16; ++r) p[r] = __builtin_amdgcn_exp2f(sc[ni][r]);
      float s0 = (p[0] + p[1]) + (p[2] + p[3]);
      float s1 = (p[4] + p[5]) + (p[6] + p[7]);
      float s2 = (p[8] + p[9]) + (p[10] + p[11]);
      float s3 = (p[12] + p[13]) + (p[14] + p[15]);
      lrun += (s0 + s1) + (s2 + s3);
#pragma unroll
      for (int ks2 = 0; ks2 < 2; ++ks2)
#pragma unroll
        for (int i = 0; i < 4; ++i) {
          unsigned lo = __float_as_uint(p[8 * ks2 + 2 * i])     + 0x8000u;
          unsigned hi = __float_as_uint(p[8 * ks2 + 2 * i + 1]) + 0x8000u;
          pa[2 * ni + ks2].w[i] = __builtin_amdgcn_perm(hi, lo, 0x07060302u);
        }
    }

    // ---- O += P V  (V rows pre-permuted so pa's k-order matches)
    __builtin_amdgcn_s_setprio(1);
#pragma unroll
    for (int f = 0; f < 8; ++f) {
      bf16x8 vb[2];
#pragma unroll
      for (int nd = 0; nd < 2; ++nd) {
        int d = nd * 32 + l31;
        vb[nd] = *(const bf16x8*)&Vts[pbuf][d * 128 + (((2 * f + h) ^ ((d + (d >> 3)) & 15)) << 3)];
      }
#pragma unroll
      for (int nd = 0; nd < 2; ++nd)
        oacc[nd] = __builtin_amdgcn_mfma_f32_32x32x16_bf16(pa[f].f, vb[nd], oacc[nd], 0, 0, 0);
    }
    __builtin_amdgcn_s_setprio(0);

    // ---- commit prefetched V (permuted positions, dc-mixed swizzle: conflict-free)
    if (t < 15) {
#pragma unroll
      for (int u = 0; u < 8; ++u) {
        int d = dc * 8 + u;
        unsigned w0 = (unsigned)vr[0].s[u] | ((unsigned)vr[1].s[u] << 16);
        unsigned w1 = (unsigned)vr[2].s[u] | ((unsigned)vr[3].s[u] << 16);
        *(u64*)&Vts[pbuf ^ 1][d * 128 + ((vchunk ^ ((d + (d >> 3)) & 15)) << 3) + vboff] =
            (u64)w0 | ((u64)w1 << 32);
      }
    }
    __syncthreads();
  }

  // ---- epilogue: combine l halves (1 shfl), normalize, store
  float l = lrun + __shfl_xor(lrun, 32, 64);
  float linv = 1.0f / l;
#pragma unroll
  for (int r = 0; r < 16; ++r) {
    int rowloc = (r & 3) + 8 * (r >> 2) + 4 * h;
    float lb = __shfl(linv, rowloc, 64);
    int row = q0 + wave * 32 + rowloc;
#pragma unroll
    for (int nd = 0; nd < 2; ++nd)
      outp[((size_t)b * NSEQ + row) * DIM + hd * 64 + nd * 32 + l31] = f2b(oacc[nd][r] * lb);
  }
}

extern "C" void kernel_launch(void* const* d_in, const int* in_sizes, int n_in,
                              void* d_out, int out_size, void* d_ws, size_t ws_size,
                              hipStream_t stream) {
  const float* x     = (const float*)d_in[0];
  const float* w_qkv = (const float*)d_in[1];
  const float* w_out = (const float*)d_in[2];
  const float* b_out = (const float*)d_in[3];
  float* outp = (float*)d_out;

  u16* xb    = (u16*)d_ws;                        // 4096*1024
  u16* wqkvb = xb    + (size_t)4096 * 1024;       // 3072*1024
  u16* woutb = wqkvb + (size_t)3072 * 1024;       // 1024*1024
  u16* qkvb  = woutb + (size_t)1024 * 1024;       // 4096*3072
  u16* attnb = qkvb  + (size_t)4096 * 3072;       // 4096*1024

  const float C2 = 0.03125f * 1.44269504088896340736f;  // dim^-0.5 * log2(e)

  cvt_all<<<(N4_X + N4_W + N4_O) / 256, 256, 0, stream>>>(x, w_qkv, w_out,
                                                          xb, wqkvb, woutb, C2);

  gemm_bt<<<dim3(12, 32), 256, 0, stream>>>(xb, wqkvb, qkvb, nullptr, 4096, 3072, 1024, 1);
  attn<<<dim3(32, 16), 256, 0, stream>>>(qkvb, attnb);
  gemm_bt_n64<<<dim3(16, 32), 256, 0, stream>>>(attnb, woutb, outp, b_out, 4096, 1024, 1024);
}